// Round 8
// baseline (153.605 us; speedup 1.0000x reference)
//
#include <hip/hip_runtime.h>

// SSIM fused, v8: barrier-free MFMA conv + per-wave software pipelining.
// v7 post-mortem: waves stall on their own 3 sequential load batches (vmcnt),
// VALUBusy 29%. Fix = memory-level parallelism within the wave:
//   - all 12 float4 loads of a tile issued before any compute (one latency hit)
//   - each wave processes TWO col-tiles: load T0, load T1, compute T0 (covers
//     T1's latency), compute T1. ~24 loads in flight (~96 VGPRs).
//   - quantity planes + SSIM math in packed f32 (v_pk_*), ~40% fewer VALU ops.
// Structure otherwise = v7: zero barriers, per-wave private H region in LDS,
// per-wave partials. Band[i][k] = g[k-i-3], halo -8, built via __shfl.

#define IMG 512
#define NPIX (16LL * 3 * 512 * 512)
#define GX 4                 /* 512/128 */
#define GY 16                /* 512/32  */
#define NBLK (GX * GY * 48)  /* 3072 blocks */
#define NPART (NBLK * 4)     /* per-wave partials: 48 KB */
#define HP 56                /* hbuf hrow pitch (shorts): 112 B -> aligned b128 */

typedef short v8s __attribute__((ext_vector_type(8)));   // 8 x bf16 (4 VGPRs)
typedef float v4f __attribute__((ext_vector_type(4)));   // MFMA accumulator
typedef __bf16 bf2 __attribute__((ext_vector_type(2)));
typedef float f2  __attribute__((ext_vector_type(2)));

static __device__ __forceinline__ int cvtpk2(f2 v) {     // v_cvt_pk_bf16_f32
    bf2 r = __builtin_convertvector(v, bf2);
    return __builtin_bit_cast(int, r);
}
static __device__ __forceinline__ unsigned f2bf(float f) {
    unsigned u = __float_as_uint(f);
    return (u + 0x7FFFu + ((u >> 16) & 1u)) >> 16;
}

struct Tile { float4 a[3][2]; float4 b[3][2]; };         // 12 float4 = 48 VGPRs

template <bool EDGE>
static __device__ __forceinline__ void load_tile(
    const float* __restrict__ p1, const float* __restrict__ p2,
    int tx0, int ty0, int ct, int lm, int quad, Tile& t)
{
    #pragma unroll
    for (int rt = 0; rt < 3; ++rt) {
        const int grow = ty0 - 8 + rt * 16 + lm;
        const int gcol = tx0 - 8 + ct * 16 + quad * 8;   // 4-aligned
        if (!EDGE) {
            const float* r1 = p1 + (size_t)grow * IMG + gcol;
            const float* r2 = p2 + (size_t)grow * IMG + gcol;
            t.a[rt][0] = *(const float4*)r1;  t.a[rt][1] = *(const float4*)(r1 + 4);
            t.b[rt][0] = *(const float4*)r2;  t.b[rt][1] = *(const float4*)(r2 + 4);
        } else {
            float4 z4; z4.x = z4.y = z4.z = z4.w = 0.f;
            t.a[rt][0] = t.a[rt][1] = t.b[rt][0] = t.b[rt][1] = z4;
            if ((unsigned)grow < IMG) {
                const float* r1 = p1 + (size_t)grow * IMG;
                const float* r2 = p2 + (size_t)grow * IMG;
                if ((unsigned)gcol < IMG) {
                    t.a[rt][0] = *(const float4*)(r1 + gcol);
                    t.b[rt][0] = *(const float4*)(r2 + gcol);
                }
                if ((unsigned)(gcol + 4) < IMG) {
                    t.a[rt][1] = *(const float4*)(r1 + gcol + 4);
                    t.b[rt][1] = *(const float4*)(r2 + gcol + 4);
                }
            }
        }
    }
}

static __device__ __forceinline__ void compute_tile(
    const Tile& t, v8s band, short (*hw)[16][HP],
    int lm, int quad, f2& vsum)
{
    const v4f zacc = {0.f, 0.f, 0.f, 0.f};
    // ---- h-pass: 3 row-tiles x 4 planes, packed conversions ----
    #pragma unroll
    for (int rt = 0; rt < 3; ++rt) {
        const float4 a0 = t.a[rt][0], a1 = t.a[rt][1];
        const float4 b0 = t.b[rt][0], b1 = t.b[rt][1];
        f2 a0l; a0l.x = a0.x; a0l.y = a0.y;   f2 a0h; a0h.x = a0.z; a0h.y = a0.w;
        f2 a1l; a1l.x = a1.x; a1l.y = a1.y;   f2 a1h; a1h.x = a1.z; a1h.y = a1.w;
        f2 b0l; b0l.x = b0.x; b0l.y = b0.y;   f2 b0h; b0h.x = b0.z; b0h.y = b0.w;
        f2 b1l; b1l.x = b1.x; b1l.y = b1.y;   f2 b1h; b1h.x = b1.z; b1h.y = b1.w;

        v8s A[4]; int4 w;
        w.x = cvtpk2(a0l); w.y = cvtpk2(a0h); w.z = cvtpk2(a1l); w.w = cvtpk2(a1h);
        A[0] = __builtin_bit_cast(v8s, w);
        w.x = cvtpk2(b0l); w.y = cvtpk2(b0h); w.z = cvtpk2(b1l); w.w = cvtpk2(b1h);
        A[1] = __builtin_bit_cast(v8s, w);
        w.x = cvtpk2(__builtin_elementwise_fma(a0l, a0l, b0l * b0l));   // v_pk_fma
        w.y = cvtpk2(__builtin_elementwise_fma(a0h, a0h, b0h * b0h));
        w.z = cvtpk2(__builtin_elementwise_fma(a1l, a1l, b1l * b1l));
        w.w = cvtpk2(__builtin_elementwise_fma(a1h, a1h, b1h * b1h));
        A[2] = __builtin_bit_cast(v8s, w);
        w.x = cvtpk2(a0l * b0l); w.y = cvtpk2(a0h * b0h);
        w.z = cvtpk2(a1l * b1l); w.w = cvtpk2(a1h * b1h);
        A[3] = __builtin_bit_cast(v8s, w);

        #pragma unroll
        for (int p = 0; p < 4; ++p) {
            const v4f acc = __builtin_amdgcn_mfma_f32_16x16x32_bf16(A[p], band, zacc, 0, 0, 0);
            // D C-layout: col = lm, rows rt*16 + quad*4 + reg -> col-major write.
            int2 w2;
            f2 lo; lo.x = acc[0]; lo.y = acc[1];
            f2 hi; hi.x = acc[2]; hi.y = acc[3];
            w2.x = cvtpk2(lo); w2.y = cvtpk2(hi);
            *(int2*)&hw[p][lm][rt * 16 + quad * 4] = w2;
        }
    }

    // ---- v-pass: 2 out row-tiles x 4 planes, SSIM in packed f32 ----
    const f2 C1v = {1e-4f, 1e-4f};        // 0.01^2
    const f2 C2v = {9e-4f, 9e-4f};        // 0.03^2
    const f2 two = {2.f, 2.f};
    #pragma unroll
    for (int t2 = 0; t2 < 2; ++t2) {
        const int r0v = t2 * 16;
        v4f acc[4];
        #pragma unroll
        for (int p = 0; p < 4; ++p) {
            const v8s hf = *(const v8s*)&hw[p][lm][r0v + quad * 8];
            acc[p] = __builtin_amdgcn_mfma_f32_16x16x32_bf16(band, hf, zacc, 0, 0, 0);
        }
        #pragma unroll
        for (int h = 0; h < 2; ++h) {      // reg pairs (0,1) and (2,3)
            f2 m1; m1.x = acc[0][2 * h]; m1.y = acc[0][2 * h + 1];
            f2 m2; m2.x = acc[1][2 * h]; m2.y = acc[1][2 * h + 1];
            f2 es; es.x = acc[2][2 * h]; es.y = acc[2][2 * h + 1];
            f2 ex; ex.x = acc[3][2 * h]; ex.y = acc[3][2 * h + 1];
            const f2 m1s = m1 * m1, m2s = m2 * m2, m12 = m1 * m2;
            const f2 sig = es - m1s - m2s;                  // sig1_sq + sig2_sq
            const f2 s12 = ex - m12;
            const f2 num = __builtin_elementwise_fma(two, m12, C1v) *
                           __builtin_elementwise_fma(two, s12, C2v);
            const f2 den = (m1s + m2s + C1v) * (sig + C2v);
            f2 r; r.x = __builtin_amdgcn_rcpf(den.x); r.y = __builtin_amdgcn_rcpf(den.y);
            vsum = __builtin_elementwise_fma(num, r, vsum);
        }
    }
}

__global__ __launch_bounds__(256, 4) void ssim_kernel(
    const float* __restrict__ img1,
    const float* __restrict__ img2,
    const float* __restrict__ win,
    float* __restrict__ partial)
{
    // Per-wave private H planes: [wave][plane][col][hrow-pitch]. 28672 B.
    __shared__ __align__(16) short hbuf[4][4][16][HP];

    const int tid  = threadIdx.x;
    const int lane = tid & 63;
    const int wave = tid >> 6;
    const int lm   = lane & 15;
    const int quad = lane >> 4;

    const int bx = blockIdx.x, by = blockIdx.y, z = blockIdx.z;
    const int tx0 = bx * 128, ty0 = by * 32;

    // Band fragment via shuffle: value g[k-i-3], i = lane&15, k = quad*8+j.
    float gl = 0.f;
    if (lane < 11) gl = win[55 + lane] * rsqrtf(win[60]);
    v8s band;
    #pragma unroll
    for (int j = 0; j < 8; ++j) {
        const int t  = quad * 8 + j - lm - 3;
        const int tc = ((unsigned)t > 10u) ? 11 : t;   // lane 11 holds 0
        band[j] = (short)f2bf(__shfl(gl, tc));
    }

    const size_t zoff = (size_t)z * IMG * IMG;
    const float* p1 = img1 + zoff;
    const float* p2 = img2 + zoff;

    const int ct0 = wave * 2, ct1 = wave * 2 + 1;
    const bool interior = (bx > 0) & (bx < GX - 1) & (by > 0) & (by < GY - 1);

    // ---- software pipeline: issue ALL loads for both tiles, then compute ----
    Tile t0, t1;
    if (interior) {
        load_tile<false>(p1, p2, tx0, ty0, ct0, lm, quad, t0);
        load_tile<false>(p1, p2, tx0, ty0, ct1, lm, quad, t1);
    } else {
        load_tile<true >(p1, p2, tx0, ty0, ct0, lm, quad, t0);
        load_tile<true >(p1, p2, tx0, ty0, ct1, lm, quad, t1);
    }

    f2 vsum = {0.f, 0.f};
    compute_tile(t0, band, hbuf[wave], lm, quad, vsum);   // covers t1's latency
    compute_tile(t1, band, hbuf[wave], lm, quad, vsum);

    // ---- wave reduction -> per-wave partial (no barriers anywhere) ----
    float vs = vsum.x + vsum.y;
    #pragma unroll
    for (int off = 32; off > 0; off >>= 1)
        vs += __shfl_down(vs, off, 64);
    if (lane == 0) {
        const int bidx = (z * (int)gridDim.y + by) * (int)gridDim.x + bx;
        partial[bidx * 4 + wave] = vs;
    }
}

__global__ __launch_bounds__(512) void finalize_kernel(
    const float* __restrict__ partial, float* __restrict__ out)
{
    __shared__ float red[8];
    const float4* p4 = (const float4*)partial;
    float s = 0.f;
    for (int i = threadIdx.x; i < NPART / 4; i += 512) {   // 6 iterations
        float4 t = p4[i];
        s += (t.x + t.y) + (t.z + t.w);
    }
    #pragma unroll
    for (int off = 32; off > 0; off >>= 1)
        s += __shfl_down(s, off, 64);
    if ((threadIdx.x & 63) == 0) red[threadIdx.x >> 6] = s;
    __syncthreads();
    if (threadIdx.x == 0) {
        float t = 0.f;
        #pragma unroll
        for (int i = 0; i < 8; ++i) t += red[i];
        out[0] = 1.0f - t / (float)NPIX;
    }
}

extern "C" void kernel_launch(void* const* d_in, const int* in_sizes, int n_in,
                              void* d_out, int out_size, void* d_ws, size_t ws_size,
                              hipStream_t stream) {
    const float* img1 = (const float*)d_in[0];
    const float* img2 = (const float*)d_in[1];
    const float* win  = (const float*)d_in[2];
    float* partialb = (float*)d_ws;  // NPART floats = 48 KB; every slot written each call

    dim3 grid(GX, GY, 48);
    ssim_kernel<<<grid, dim3(256), 0, stream>>>(img1, img2, win, partialb);
    finalize_kernel<<<1, dim3(512), 0, stream>>>(partialb, (float*)d_out);
}

// Round 9
// 142.602 us; speedup vs baseline: 1.0772x; 1.0772x over previous
//
#include <hip/hip_runtime.h>

// SSIM fused, v9: v8's two-tile software pipeline with the spill FIXED.
// v8 post-mortem: __launch_bounds__(256,4) capped VGPR at 128; the 96-VGPR
// load window spilled to scratch (WRITE_SIZE 0.2->3.2 MB), serializing
// everything. v9: __launch_bounds__(256,2) -> 256 VGPR cap, flat unrolled
// arrays, loads for BOTH tiles issued before any compute (~24 KB in flight
// per wave). Per-TILE interior flags (82% of tiles unguarded vs 44% of
// blocks in v8). Structure otherwise v7/v8: zero barriers, per-wave private
// H region, per-wave partials. Band[i][k] = g[k-i-3], halo -8, via __shfl.

#define IMG 512
#define NPIX (16LL * 3 * 512 * 512)
#define GX 4                 /* 512/128 */
#define GY 16                /* 512/32  */
#define NBLK (GX * GY * 48)  /* 3072 blocks */
#define NPART (NBLK * 4)     /* per-wave partials: 48 KB */
#define HP 56                /* hbuf hrow pitch (shorts): 112 B -> aligned b128, 2-way banks */

typedef short v8s __attribute__((ext_vector_type(8)));   // 8 x bf16 (4 VGPRs)
typedef float v4f __attribute__((ext_vector_type(4)));   // MFMA accumulator
typedef __bf16 bf2 __attribute__((ext_vector_type(2)));
typedef float f2  __attribute__((ext_vector_type(2)));

static __device__ __forceinline__ int cvtpk2(f2 v) {     // v_cvt_pk_bf16_f32
    bf2 r = __builtin_convertvector(v, bf2);
    return __builtin_bit_cast(int, r);
}
static __device__ __forceinline__ unsigned f2bf(float f) {
    unsigned u = __float_as_uint(f);
    return (u + 0x7FFFu + ((u >> 16) & 1u)) >> 16;
}

// Loads for one 16-col tile: 12 float4 into caller's flat arrays.
template <bool EDGE>
static __device__ __forceinline__ void load_tile(
    const float* __restrict__ p1, const float* __restrict__ p2,
    int ty0, int gct, int lm, int quad,
    float4 a[3][2], float4 b[3][2])
{
    const int gcol = gct * 16 - 8 + quad * 8;            // 4-aligned
    #pragma unroll
    for (int rt = 0; rt < 3; ++rt) {
        const int grow = ty0 - 8 + rt * 16 + lm;
        if (!EDGE) {
            const float* r1 = p1 + (size_t)grow * IMG + gcol;
            const float* r2 = p2 + (size_t)grow * IMG + gcol;
            a[rt][0] = *(const float4*)r1;  a[rt][1] = *(const float4*)(r1 + 4);
            b[rt][0] = *(const float4*)r2;  b[rt][1] = *(const float4*)(r2 + 4);
        } else {
            float4 z4; z4.x = z4.y = z4.z = z4.w = 0.f;
            a[rt][0] = a[rt][1] = b[rt][0] = b[rt][1] = z4;
            if ((unsigned)grow < IMG) {
                const float* r1 = p1 + (size_t)grow * IMG;
                const float* r2 = p2 + (size_t)grow * IMG;
                if ((unsigned)gcol < IMG) {
                    a[rt][0] = *(const float4*)(r1 + gcol);
                    b[rt][0] = *(const float4*)(r2 + gcol);
                }
                if ((unsigned)(gcol + 4) < IMG) {
                    a[rt][1] = *(const float4*)(r1 + gcol + 4);
                    b[rt][1] = *(const float4*)(r2 + gcol + 4);
                }
            }
        }
    }
}

static __device__ __forceinline__ void compute_tile(
    const float4 a[3][2], const float4 b[3][2], v8s band,
    short (*hw)[16][HP], int lm, int quad, f2& vsum)
{
    const v4f zacc = {0.f, 0.f, 0.f, 0.f};
    // ---- h-pass: 3 row-tiles x 4 planes, packed conversions ----
    #pragma unroll
    for (int rt = 0; rt < 3; ++rt) {
        const float4 a0 = a[rt][0], a1 = a[rt][1];
        const float4 b0 = b[rt][0], b1 = b[rt][1];
        f2 a0l; a0l.x = a0.x; a0l.y = a0.y;   f2 a0h; a0h.x = a0.z; a0h.y = a0.w;
        f2 a1l; a1l.x = a1.x; a1l.y = a1.y;   f2 a1h; a1h.x = a1.z; a1h.y = a1.w;
        f2 b0l; b0l.x = b0.x; b0l.y = b0.y;   f2 b0h; b0h.x = b0.z; b0h.y = b0.w;
        f2 b1l; b1l.x = b1.x; b1l.y = b1.y;   f2 b1h; b1h.x = b1.z; b1h.y = b1.w;

        v8s A[4]; int4 w;
        w.x = cvtpk2(a0l); w.y = cvtpk2(a0h); w.z = cvtpk2(a1l); w.w = cvtpk2(a1h);
        A[0] = __builtin_bit_cast(v8s, w);
        w.x = cvtpk2(b0l); w.y = cvtpk2(b0h); w.z = cvtpk2(b1l); w.w = cvtpk2(b1h);
        A[1] = __builtin_bit_cast(v8s, w);
        w.x = cvtpk2(__builtin_elementwise_fma(a0l, a0l, b0l * b0l));
        w.y = cvtpk2(__builtin_elementwise_fma(a0h, a0h, b0h * b0h));
        w.z = cvtpk2(__builtin_elementwise_fma(a1l, a1l, b1l * b1l));
        w.w = cvtpk2(__builtin_elementwise_fma(a1h, a1h, b1h * b1h));
        A[2] = __builtin_bit_cast(v8s, w);
        w.x = cvtpk2(a0l * b0l); w.y = cvtpk2(a0h * b0h);
        w.z = cvtpk2(a1l * b1l); w.w = cvtpk2(a1h * b1h);
        A[3] = __builtin_bit_cast(v8s, w);

        #pragma unroll
        for (int p = 0; p < 4; ++p) {
            const v4f acc = __builtin_amdgcn_mfma_f32_16x16x32_bf16(A[p], band, zacc, 0, 0, 0);
            // D C-layout: col = lm, rows rt*16 + quad*4 + reg -> col-major write.
            int2 w2;
            f2 lo; lo.x = acc[0]; lo.y = acc[1];
            f2 hi; hi.x = acc[2]; hi.y = acc[3];
            w2.x = cvtpk2(lo); w2.y = cvtpk2(hi);
            *(int2*)&hw[p][lm][rt * 16 + quad * 4] = w2;
        }
    }

    // ---- v-pass: 2 out row-tiles x 4 planes, SSIM in packed f32 ----
    const f2 C1v = {1e-4f, 1e-4f};        // 0.01^2
    const f2 C2v = {9e-4f, 9e-4f};        // 0.03^2
    const f2 two = {2.f, 2.f};
    #pragma unroll
    for (int t2 = 0; t2 < 2; ++t2) {
        const int r0v = t2 * 16;
        v4f acc[4];
        #pragma unroll
        for (int p = 0; p < 4; ++p) {
            const v8s hf = *(const v8s*)&hw[p][lm][r0v + quad * 8];
            acc[p] = __builtin_amdgcn_mfma_f32_16x16x32_bf16(band, hf, zacc, 0, 0, 0);
        }
        #pragma unroll
        for (int h = 0; h < 2; ++h) {
            f2 m1; m1.x = acc[0][2 * h]; m1.y = acc[0][2 * h + 1];
            f2 m2; m2.x = acc[1][2 * h]; m2.y = acc[1][2 * h + 1];
            f2 es; es.x = acc[2][2 * h]; es.y = acc[2][2 * h + 1];
            f2 ex; ex.x = acc[3][2 * h]; ex.y = acc[3][2 * h + 1];
            const f2 m1s = m1 * m1, m2s = m2 * m2, m12 = m1 * m2;
            const f2 sig = es - m1s - m2s;                  // sig1_sq + sig2_sq
            const f2 s12 = ex - m12;
            const f2 num = __builtin_elementwise_fma(two, m12, C1v) *
                           __builtin_elementwise_fma(two, s12, C2v);
            const f2 den = (m1s + m2s + C1v) * (sig + C2v);
            f2 r; r.x = __builtin_amdgcn_rcpf(den.x); r.y = __builtin_amdgcn_rcpf(den.y);
            vsum = __builtin_elementwise_fma(num, r, vsum);
        }
    }
}

__global__ __launch_bounds__(256, 2) void ssim_kernel(
    const float* __restrict__ img1,
    const float* __restrict__ img2,
    const float* __restrict__ win,
    float* __restrict__ partial)
{
    // Per-wave private H planes: [wave][plane][col][hrow-pitch]. 28672 B.
    __shared__ __align__(16) short hbuf[4][4][16][HP];

    const int tid  = threadIdx.x;
    const int lane = tid & 63;
    const int wave = tid >> 6;
    const int lm   = lane & 15;
    const int quad = lane >> 4;

    const int bx = blockIdx.x, by = blockIdx.y, z = blockIdx.z;
    const int ty0 = by * 32;

    // Band fragment via shuffle: value g[k-i-3], i = lane&15, k = quad*8+j.
    float gl = 0.f;
    if (lane < 11) gl = win[55 + lane] * rsqrtf(win[60]);
    v8s band;
    #pragma unroll
    for (int j = 0; j < 8; ++j) {
        const int t  = quad * 8 + j - lm - 3;
        const int tc = ((unsigned)t > 10u) ? 11 : t;   // lane 11 holds 0
        band[j] = (short)f2bf(__shfl(gl, tc));
    }

    const size_t zoff = (size_t)z * IMG * IMG;
    const float* p1 = img1 + zoff;
    const float* p2 = img2 + zoff;

    // Global col-tile indices (0..31); per-TILE interior test.
    const int gct0 = bx * 8 + wave * 2;
    const int gct1 = gct0 + 1;
    const bool rowok = (by > 0) & (by < GY - 1);
    const bool int0  = rowok & (gct0 > 0) & (gct0 < 31);
    const bool int1  = rowok & (gct1 > 0) & (gct1 < 31);

    // ---- issue ALL 24 loads (both tiles) before any compute ----
    float4 a0[3][2], b0[3][2], a1[3][2], b1[3][2];
    if (int0) load_tile<false>(p1, p2, ty0, gct0, lm, quad, a0, b0);
    else      load_tile<true >(p1, p2, ty0, gct0, lm, quad, a0, b0);
    if (int1) load_tile<false>(p1, p2, ty0, gct1, lm, quad, a1, b1);
    else      load_tile<true >(p1, p2, ty0, gct1, lm, quad, a1, b1);

    f2 vsum = {0.f, 0.f};
    compute_tile(a0, b0, band, hbuf[wave], lm, quad, vsum);   // covers t1 latency
    compute_tile(a1, b1, band, hbuf[wave], lm, quad, vsum);

    // ---- wave reduction -> per-wave partial (no barriers anywhere) ----
    float vs = vsum.x + vsum.y;
    #pragma unroll
    for (int off = 32; off > 0; off >>= 1)
        vs += __shfl_down(vs, off, 64);
    if (lane == 0) {
        const int bidx = (z * (int)gridDim.y + by) * (int)gridDim.x + bx;
        partial[bidx * 4 + wave] = vs;
    }
}

__global__ __launch_bounds__(512) void finalize_kernel(
    const float* __restrict__ partial, float* __restrict__ out)
{
    __shared__ float red[8];
    const float4* p4 = (const float4*)partial;
    float s = 0.f;
    for (int i = threadIdx.x; i < NPART / 4; i += 512) {   // 6 iterations
        float4 t = p4[i];
        s += (t.x + t.y) + (t.z + t.w);
    }
    #pragma unroll
    for (int off = 32; off > 0; off >>= 1)
        s += __shfl_down(s, off, 64);
    if ((threadIdx.x & 63) == 0) red[threadIdx.x >> 6] = s;
    __syncthreads();
    if (threadIdx.x == 0) {
        float t = 0.f;
        #pragma unroll
        for (int i = 0; i < 8; ++i) t += red[i];
        out[0] = 1.0f - t / (float)NPIX;
    }
}

extern "C" void kernel_launch(void* const* d_in, const int* in_sizes, int n_in,
                              void* d_out, int out_size, void* d_ws, size_t ws_size,
                              hipStream_t stream) {
    const float* img1 = (const float*)d_in[0];
    const float* img2 = (const float*)d_in[1];
    const float* win  = (const float*)d_in[2];
    float* partialb = (float*)d_ws;  // NPART floats = 48 KB; every slot written each call

    dim3 grid(GX, GY, 48);
    ssim_kernel<<<grid, dim3(256), 0, stream>>>(img1, img2, win, partialb);
    finalize_kernel<<<1, dim3(512), 0, stream>>>(partialb, (float*)d_out);
}